// Round 6
// baseline (450.179 us; speedup 1.0000x reference)
//
#include <hip/hip_runtime.h>

#define H 256
#define W 256
#define BATCH 8
#define CIN 16
#define TW 32
#define TH 4
#define HWC (TW + 2)        // 34 halo cols
#define HHC (TH + 2)        // 6 halo rows
#define NHALO (HWC * HHC)   // 204 halo pixels
#define NPIX_TOTAL (BATCH * H * W)   // 524288
#define GAP_TAU 8e-3f

typedef __attribute__((ext_vector_type(8))) short short8;       // 8 fp16 bit-patterns
typedef __attribute__((ext_vector_type(8))) _Float16 half8;     // MFMA A/B frag
typedef __attribute__((ext_vector_type(4))) float f32x4;        // MFMA C/D frag

union S8H8 { short8 s; half8 h; };
__device__ __forceinline__ half8 as_h8(short8 s) { S8H8 u; u.s = s; return u.h; }
union HU { _Float16 h; unsigned short u; };
__device__ __forceinline__ unsigned short f2h_bits(float f) { HU u; u.h = (_Float16)f; return u.u; }

__device__ __forceinline__ float4 add4(float4 a, float4 b) {
    return make_float4(a.x + b.x, a.y + b.y, a.z + b.z, a.w + b.w);
}
__device__ __forceinline__ float max4(float4 a) {
    return fmaxf(fmaxf(a.x, a.y), fmaxf(a.z, a.w));
}

// weight [oc][ic][3][3] fp32 ->
//   wt  fp16 bits, x64-scaled, layout [tap][n=oc][k=ic]      (36864 shorts)
//   wT  fp32 exact, layout [tap][ic][oc]  (fixup, coalesced) (36864 floats)
// also zeroes fix_cnt (replaces a memset dispatch)
__global__ void wprep_kernel(const float* __restrict__ w, unsigned short* __restrict__ wt,
                             float* __restrict__ wT, unsigned* __restrict__ fix_cnt) {
    int i = blockIdx.x * 256 + threadIdx.x;   // 9*64*64 = 36864
    if (blockIdx.x == 0 && threadIdx.x < 4) fix_cnt[threadIdx.x] = 0u;
    if (i >= 36864) return;
    int ic  = i & 63;
    int oc  = (i >> 6) & 63;
    int tap = i >> 12;
    float v = w[(oc * 64 + ic) * 9 + tap];
    wt[(tap * 64 + oc) * 64 + ic] = f2h_bits(v * 64.0f);
    wT[(tap * 64 + ic) * 64 + oc] = v;
}

__global__ __launch_bounds__(256, 4) void ssconv_mfma_kernel(
    const float* __restrict__ x, const int* __restrict__ gidx,
    const unsigned short* __restrict__ wt, const float* __restrict__ bias,
    float* __restrict__ out_sel, float* __restrict__ out_idx,
    unsigned* __restrict__ fix_cnt, unsigned* __restrict__ fix_list, unsigned fix_cap)
{
    __shared__ unsigned short hHi[NHALO * 16];            // 6528 B (x as fp16)
    __shared__ int gsL[NHALO];                            // 816 B
    // union: 2x B-tap buffers (2*9216 B) during K-loop, epilogue scratch (17408 B)
    __shared__ __align__(16) unsigned short bufS[9216];   // 18432 B

    const int tid = threadIdx.x;
    const int x0 = blockIdx.x * TW;
    const int y0 = blockIdx.y * TH;
    const int bz = blockIdx.z;

    // ---- stage halo as fp16 + group map ----
    if (tid < NHALO) {
        int r = tid / HWC, c = tid % HWC;
        int hy = y0 + r - 1, hx = x0 + c - 1;
        bool ok = (hy >= 0) && (hy < H) && (hx >= 0) && (hx < W);
        float4 a0 = make_float4(0, 0, 0, 0), a1 = a0, a2 = a0, a3 = a0;
        int g = 0;
        if (ok) {
            const float4* src = (const float4*)(x + (((size_t)bz * H + hy) * W + hx) * CIN);
            a0 = src[0]; a1 = src[1]; a2 = src[2]; a3 = src[3];
            g = gidx[((size_t)bz * H + hy) * W + hx];
        }
        gsL[tid] = g;
        short8 v0, v1;
        v0[0] = (short)f2h_bits(a0.x); v0[1] = (short)f2h_bits(a0.y);
        v0[2] = (short)f2h_bits(a0.z); v0[3] = (short)f2h_bits(a0.w);
        v0[4] = (short)f2h_bits(a1.x); v0[5] = (short)f2h_bits(a1.y);
        v0[6] = (short)f2h_bits(a1.z); v0[7] = (short)f2h_bits(a1.w);
        v1[0] = (short)f2h_bits(a2.x); v1[1] = (short)f2h_bits(a2.y);
        v1[2] = (short)f2h_bits(a2.z); v1[3] = (short)f2h_bits(a2.w);
        v1[4] = (short)f2h_bits(a3.x); v1[5] = (short)f2h_bits(a3.y);
        v1[6] = (short)f2h_bits(a3.z); v1[7] = (short)f2h_bits(a3.w);
        *(short8*)&hHi[tid * 16 + 0] = v0;
        *(short8*)&hHi[tid * 16 + 8] = v1;
    }

    const int wvid = tid >> 6;        // wave id 0..3 -> tile row
    const int L    = tid & 63;
    const int q    = L >> 4;          // quad
    const int lm   = L & 15;

    unsigned short* bufA = bufS;          // 64 rows x 72 shorts = 4608 shorts
    unsigned short* bufB = bufS + 4608;

    // ---- stage B(tap=0) into bufA: 512 short8 chunks, 2 per thread ----
    {
        int i0 = tid, i1 = 256 + tid;             // n = i>>3, ko = i&7
        short8 v0 = *(const short8*)(wt + (i0 >> 3) * 64 + (i0 & 7) * 8);
        short8 v1 = *(const short8*)(wt + (i1 >> 3) * 64 + (i1 & 7) * 8);
        *(short8*)(bufA + (i0 >> 3) * 72 + (i0 & 7) * 8) = v0;
        *(short8*)(bufA + (i1 >> 3) * 72 + (i1 & 7) * 8) = v1;
    }
    __syncthreads();

    f32x4 acc0[4] = {}, acc1[4] = {};   // 2 m-tiles x 4 n-tiles, 16x16 each

#pragma unroll 1
    for (int tap = 0; tap < 9; ++tap) {
        unsigned short* cur = (tap & 1) ? bufB : bufA;
        unsigned short* nxt = (tap & 1) ? bufA : bufB;

        // prefetch next tap's weights into registers (stores after compute)
        short8 p0, p1;
        if (tap < 8) {
            const unsigned short* wsrc = wt + (size_t)(tap + 1) * 4096;
            int i0 = tid, i1 = 256 + tid;
            p0 = *(const short8*)(wsrc + (i0 >> 3) * 64 + (i0 & 7) * 8);
            p1 = *(const short8*)(wsrc + (i1 >> 3) * 64 + (i1 & 7) * 8);
        }

        const int dy = tap / 3, dx = tap % 3;
        const int hb0 = (wvid + dy) * HWC + lm + dx;   // m-tile 0 halo pixel
        const int hb1 = hb0 + 16;                      // m-tile 1
        const int g0 = gsL[hb0];
        const int g1 = gsL[hb1];

#pragma unroll
        for (int ks = 0; ks < 2; ++ks) {
            const int gk = ks * 2 + (q >> 1);
            const int c0 = (q & 1) * 8;
            short8 z = (short8)0;
            short8 ah0 = *(const short8*)&hHi[hb0 * 16 + c0];
            short8 ah1 = *(const short8*)&hHi[hb1 * 16 + c0];
            ah0 = (g0 == gk) ? ah0 : z;
            ah1 = (g1 == gk) ? ah1 : z;

            short8 bh[4];
#pragma unroll
            for (int nt = 0; nt < 4; ++nt)
                bh[nt] = *(const short8*)(cur + (nt * 16 + lm) * 72 + ks * 32 + q * 8);
#pragma unroll
            for (int nt = 0; nt < 4; ++nt) {
                acc0[nt] = __builtin_amdgcn_mfma_f32_16x16x32_f16(as_h8(ah0), as_h8(bh[nt]), acc0[nt], 0, 0, 0);
                acc1[nt] = __builtin_amdgcn_mfma_f32_16x16x32_f16(as_h8(ah1), as_h8(bh[nt]), acc1[nt], 0, 0, 0);
            }
        }

        if (tap < 8) {
            int i0 = tid, i1 = 256 + tid;
            *(short8*)(nxt + (i0 >> 3) * 72 + (i0 & 7) * 8) = p0;
            *(short8*)(nxt + (i1 >> 3) * 72 + (i1 & 7) * 8) = p1;
        }
        __syncthreads();
    }

    // ---- epilogue: two passes (m-tile 0, then 1), 17408 B scratch in bufS ----
    const float SH = 0.015625f;          // 1/64 (weights pre-scaled x64)
    float* outS = (float*)bufS;          // per-wave region: 16 px * 68 floats

#pragma unroll 1
    for (int mt = 0; mt < 2; ++mt) {
        if (mt) __syncthreads();         // pass-0 consumption done before overwrite
        f32x4* am = mt ? acc1 : acc0;
#pragma unroll
        for (int nt = 0; nt < 4; ++nt) {
#pragma unroll
            for (int r = 0; r < 4; ++r) {
                outS[wvid * 1088 + (q * 4 + r) * 68 + nt * 16 + lm] = am[nt][r] * SH;
            }
        }
        __syncthreads();

        // consume: 64 pixels, 4 threads/pixel (one group of 16 ch each)
        int p  = tid >> 2;               // 0..63: pw(4) x px16(16)
        int hh = tid & 3;                // group
        int pw = p >> 4, px16 = p & 15;
        const float4* srcp = (const float4*)(outS + pw * 1088 + px16 * 68 + hh * 16);
        const float4* bb = (const float4*)(bias + hh * 16);
        float4 r0 = add4(srcp[0], bb[0]), r1 = add4(srcp[1], bb[1]);
        float4 r2 = add4(srcp[2], bb[2]), r3 = add4(srcp[3], bb[3]);

        float m  = fmaxf(fmaxf(max4(r0), max4(r1)), fmaxf(max4(r2), max4(r3)));
        float v1 = __shfl_xor(m, 1, 64);   // group hh^1's max (same pixel)
        float v2 = __shfl_xor(m, 2, 64);   // group hh^2
        float v3 = __shfl_xor(m, 3, 64);   // group hh^3

        float g0 = (hh == 0) ? m  : (hh == 1) ? v1 : (hh == 2) ? v2 : v3;
        float g1 = (hh == 0) ? v1 : (hh == 1) ? m  : (hh == 2) ? v3 : v2;
        float g2 = (hh == 0) ? v2 : (hh == 1) ? v3 : (hh == 2) ? m  : v1;
        float g3 = (hh == 0) ? v3 : (hh == 1) ? v2 : (hh == 2) ? v1 : m;

        int bg = 0; float best = g0;
        if (g1 > best) { best = g1; bg = 1; }
        if (g2 > best) { best = g2; bg = 2; }
        if (g3 > best) { best = g3; bg = 3; }

        int gy = y0 + pw, gx = x0 + mt * 16 + px16;
        size_t opix = ((size_t)bz * H + gy) * W + gx;
        if (hh == bg) {
            float4* os = (float4*)(out_sel + opix * 16);
            os[0] = r0; os[1] = r1; os[2] = r2; os[3] = r3;
        }
        if (hh == 0) {
            out_idx[opix] = (float)bg;
            float o1 = (bg == 0) ? fmaxf(g1, fmaxf(g2, g3))
                     : (bg == 1) ? fmaxf(g0, fmaxf(g2, g3))
                     : (bg == 2) ? fmaxf(g0, fmaxf(g1, g3))
                                 : fmaxf(g0, fmaxf(g1, g2));
            if (best - o1 < GAP_TAU) {
                unsigned slot = atomicAdd(fix_cnt, 1u);
                if (slot < fix_cap) fix_list[slot] = (unsigned)opix;
            }
        }
    }
}

// fp64 exact recompute; one wave per pixel, lane = oc. Uses wT [tap][ic][oc]
// (lane-coalesced). If the flag list overflowed its cap, deterministically
// recompute ALL pixels instead (slow path; output never depends on atomic order).
__global__ void fixup_kernel(const float* __restrict__ x, const int* __restrict__ gidx,
                             const float* __restrict__ wT, const float* __restrict__ bias,
                             float* __restrict__ out_sel, float* __restrict__ out_idx,
                             const unsigned* __restrict__ fix_cnt,
                             const unsigned* __restrict__ fix_list, unsigned fix_cap)
{
    unsigned n = *fix_cnt;
    const bool full = (n > fix_cap);
    const unsigned total = full ? (unsigned)NPIX_TOTAL : n;
    const int lane = threadIdx.x & 63;
    const unsigned nwaves = gridDim.x * (blockDim.x >> 6);
    unsigned widx = blockIdx.x * (blockDim.x >> 6) + (threadIdx.x >> 6);

    for (; widx < total; widx += nwaves) {
        unsigned opix = full ? widx : fix_list[widx];
        int b  = opix >> 16;
        int y  = (opix >> 8) & 255;
        int xc = opix & 255;
        double acc = (double)bias[lane];
        for (int dy = 0; dy < 3; ++dy) {
            int yy = y + dy - 1;
            if (yy < 0 || yy >= H) continue;
            for (int dx = 0; dx < 3; ++dx) {
                int xx = xc + dx - 1;
                if (xx < 0 || xx >= W) continue;
                size_t pix = ((size_t)b * H + yy) * W + xx;
                int g = gidx[pix];
                const float* xp = x + pix * 16;
                const float* wp = wT + (size_t)((dy * 3 + dx) * 64 + g * 16) * 64 + lane;
#pragma unroll
                for (int c = 0; c < 16; ++c)
                    acc = fma((double)wp[c * 64], (double)xp[c], acc);
            }
        }
        // group max within 16-lane clusters
        double m = acc;
        m = fmax(m, __shfl_xor(m, 1, 64));
        m = fmax(m, __shfl_xor(m, 2, 64));
        m = fmax(m, __shfl_xor(m, 4, 64));
        m = fmax(m, __shfl_xor(m, 8, 64));
        double g0 = __shfl(m, 0, 64), g1 = __shfl(m, 16, 64);
        double g2 = __shfl(m, 32, 64), g3 = __shfl(m, 48, 64);
        int bg = 0; double bb = g0;
        if (g1 > bb) { bb = g1; bg = 1; }
        if (g2 > bb) { bb = g2; bg = 2; }
        if (g3 > bb) { bb = g3; bg = 3; }
        if ((lane >> 4) == bg) out_sel[(size_t)opix * 16 + (lane & 15)] = (float)acc;
        if (lane == 0) out_idx[opix] = (float)bg;
    }
}

extern "C" void kernel_launch(void* const* d_in, const int* in_sizes, int n_in,
                              void* d_out, int out_size, void* d_ws, size_t ws_size,
                              hipStream_t stream) {
    const float* x    = (const float*)d_in[0];
    const int*   gidx = (const int*)d_in[1];
    const float* w    = (const float*)d_in[2];
    const float* bias = (const float*)d_in[3];

    unsigned short* wt = (unsigned short*)d_ws;                     // 73728 B
    float* wT          = (float*)((char*)d_ws + 73728);             // 147456 B
    unsigned* fix_cnt  = (unsigned*)((char*)d_ws + 221184);         // 16 B
    unsigned* fix_list = (unsigned*)((char*)d_ws + 221200);         // up to 2 MB

    // cap sized from the workspace the harness actually gave us (det. overflow fallback otherwise)
    size_t avail = (ws_size > 221200) ? (ws_size - 221200) / 4 : 0;
    unsigned fix_cap = (unsigned)(avail < (size_t)NPIX_TOTAL ? avail : (size_t)NPIX_TOTAL);

    float* out_sel = (float*)d_out;                               // 8*256*256*16
    float* out_idx = (float*)d_out + (size_t)BATCH * H * W * CIN; // 8*256*256

    wprep_kernel<<<144, 256, 0, stream>>>(w, wt, wT, fix_cnt);

    dim3 grid(W / TW, H / TH, BATCH);   // 8 x 64 x 8 = 4096 blocks
    ssconv_mfma_kernel<<<grid, 256, 0, stream>>>(x, gidx, wt, bias, out_sel, out_idx,
                                                 fix_cnt, fix_list, fix_cap);
    fixup_kernel<<<1024, 256, 0, stream>>>(x, gidx, wT, bias, out_sel, out_idx,
                                           fix_cnt, fix_list, fix_cap);
}

// Round 7
// 244.412 us; speedup vs baseline: 1.8419x; 1.8419x over previous
//
#include <hip/hip_runtime.h>

#define H 256
#define W 256
#define BATCH 8
#define CIN 16
#define TW 32
#define TH 4
#define HWC (TW + 2)        // 34 halo cols
#define HHC (TH + 2)        // 6 halo rows
#define NHALO (HWC * HHC)   // 204 halo pixels
#define NPIX_TOTAL (BATCH * H * W)   // 524288
#define GAP_TAU 8e-3f

typedef __attribute__((ext_vector_type(8))) short short8;       // 8 fp16 bit-patterns
typedef __attribute__((ext_vector_type(8))) _Float16 half8;     // MFMA A/B frag
typedef __attribute__((ext_vector_type(4))) float f32x4;        // MFMA C/D frag

union S8H8 { short8 s; half8 h; };
__device__ __forceinline__ half8 as_h8(short8 s) { S8H8 u; u.s = s; return u.h; }
union HU { _Float16 h; unsigned short u; };
__device__ __forceinline__ unsigned short f2h_bits(float f) { HU u; u.h = (_Float16)f; return u.u; }

__device__ __forceinline__ float4 add4(float4 a, float4 b) {
    return make_float4(a.x + b.x, a.y + b.y, a.z + b.z, a.w + b.w);
}
__device__ __forceinline__ float max4(float4 a) {
    return fmaxf(fmaxf(a.x, a.y), fmaxf(a.z, a.w));
}

// weight [oc][ic][3][3] fp32 ->
//   wt  fp16 bits, x64-scaled, layout [tap][n=oc][k=ic]      (36864 shorts)
//   wT  fp32 exact, layout [tap][ic][oc]  (fixup, coalesced) (36864 floats)
// also zeroes fix_cnt (replaces a memset dispatch)
__global__ void wprep_kernel(const float* __restrict__ w, unsigned short* __restrict__ wt,
                             float* __restrict__ wT, unsigned* __restrict__ fix_cnt) {
    int i = blockIdx.x * 256 + threadIdx.x;   // 9*64*64 = 36864
    if (blockIdx.x == 0 && threadIdx.x < 4) fix_cnt[threadIdx.x] = 0u;
    if (i >= 36864) return;
    int ic  = i & 63;
    int oc  = (i >> 6) & 63;
    int tap = i >> 12;
    float v = w[(oc * 64 + ic) * 9 + tap];
    wt[(tap * 64 + oc) * 64 + ic] = f2h_bits(v * 64.0f);
    wT[(tap * 64 + ic) * 64 + oc] = v;
}

// per-pixel maxout/argmax/select for one 64-pixel m-tile; NO accumulator refs
__device__ __forceinline__ void consume_tile(
    const float* outS, const float* __restrict__ bias,
    float* __restrict__ out_sel, float* __restrict__ out_idx,
    unsigned* __restrict__ fix_cnt, unsigned* __restrict__ fix_list, unsigned fix_cap,
    int tid, int x0, int y0, int bz, int mt)
{
    int p  = tid >> 2;               // 0..63: pw(4) x px16(16)
    int hh = tid & 3;                // group
    int pw = p >> 4, px16 = p & 15;
    const float4* srcp = (const float4*)(outS + pw * 1088 + px16 * 68 + hh * 16);
    const float4* bb = (const float4*)(bias + hh * 16);
    float4 r0 = add4(srcp[0], bb[0]), r1 = add4(srcp[1], bb[1]);
    float4 r2 = add4(srcp[2], bb[2]), r3 = add4(srcp[3], bb[3]);

    float m  = fmaxf(fmaxf(max4(r0), max4(r1)), fmaxf(max4(r2), max4(r3)));
    float v1 = __shfl_xor(m, 1, 64);   // group hh^1's max (same pixel)
    float v2 = __shfl_xor(m, 2, 64);   // group hh^2
    float v3 = __shfl_xor(m, 3, 64);   // group hh^3

    float g0 = (hh == 0) ? m  : (hh == 1) ? v1 : (hh == 2) ? v2 : v3;
    float g1 = (hh == 0) ? v1 : (hh == 1) ? m  : (hh == 2) ? v3 : v2;
    float g2 = (hh == 0) ? v2 : (hh == 1) ? v3 : (hh == 2) ? m  : v1;
    float g3 = (hh == 0) ? v3 : (hh == 1) ? v2 : (hh == 2) ? v1 : m;

    int bg = 0; float best = g0;
    if (g1 > best) { best = g1; bg = 1; }
    if (g2 > best) { best = g2; bg = 2; }
    if (g3 > best) { best = g3; bg = 3; }

    int gy = y0 + pw, gx = x0 + mt * 16 + px16;
    size_t opix = ((size_t)bz * H + gy) * W + gx;
    if (hh == bg) {
        float4* os = (float4*)(out_sel + opix * 16);
        os[0] = r0; os[1] = r1; os[2] = r2; os[3] = r3;
    }
    if (hh == 0) {
        out_idx[opix] = (float)bg;
        float o1 = (bg == 0) ? fmaxf(g1, fmaxf(g2, g3))
                 : (bg == 1) ? fmaxf(g0, fmaxf(g2, g3))
                 : (bg == 2) ? fmaxf(g0, fmaxf(g1, g3))
                             : fmaxf(g0, fmaxf(g1, g2));
        if (best - o1 < GAP_TAU) {
            unsigned slot = atomicAdd(fix_cnt, 1u);
            if (slot < fix_cap) fix_list[slot] = (unsigned)opix;
        }
    }
}

// store one m-tile's accumulators to LDS scratch — accumulator named LITERALLY
// (compile-time indices only; never a runtime-selected pointer -> stays in VGPRs)
#define EPI_STORE(AM)                                                        \
    {                                                                        \
        _Pragma("unroll")                                                    \
        for (int nt = 0; nt < 4; ++nt) {                                     \
            _Pragma("unroll")                                                \
            for (int r = 0; r < 4; ++r) {                                    \
                outS[wvid * 1088 + (q * 4 + r) * 68 + nt * 16 + lm] =        \
                    AM[nt][r] * SH;                                          \
            }                                                                \
        }                                                                    \
    }

__global__ __launch_bounds__(256, 4) void ssconv_mfma_kernel(
    const float* __restrict__ x, const int* __restrict__ gidx,
    const unsigned short* __restrict__ wt, const float* __restrict__ bias,
    float* __restrict__ out_sel, float* __restrict__ out_idx,
    unsigned* __restrict__ fix_cnt, unsigned* __restrict__ fix_list, unsigned fix_cap)
{
    __shared__ unsigned short hHi[NHALO * 16];            // 6528 B (x as fp16)
    __shared__ int gsL[NHALO];                            // 816 B
    // union: 2x B-tap buffers (2*9216 B) during K-loop, epilogue scratch (17408 B)
    __shared__ __align__(16) unsigned short bufS[9216];   // 18432 B

    const int tid = threadIdx.x;
    const int x0 = blockIdx.x * TW;
    const int y0 = blockIdx.y * TH;
    const int bz = blockIdx.z;

    // ---- stage halo as fp16 + group map ----
    if (tid < NHALO) {
        int r = tid / HWC, c = tid % HWC;
        int hy = y0 + r - 1, hx = x0 + c - 1;
        bool ok = (hy >= 0) && (hy < H) && (hx >= 0) && (hx < W);
        float4 a0 = make_float4(0, 0, 0, 0), a1 = a0, a2 = a0, a3 = a0;
        int g = 0;
        if (ok) {
            const float4* src = (const float4*)(x + (((size_t)bz * H + hy) * W + hx) * CIN);
            a0 = src[0]; a1 = src[1]; a2 = src[2]; a3 = src[3];
            g = gidx[((size_t)bz * H + hy) * W + hx];
        }
        gsL[tid] = g;
        short8 v0, v1;
        v0[0] = (short)f2h_bits(a0.x); v0[1] = (short)f2h_bits(a0.y);
        v0[2] = (short)f2h_bits(a0.z); v0[3] = (short)f2h_bits(a0.w);
        v0[4] = (short)f2h_bits(a1.x); v0[5] = (short)f2h_bits(a1.y);
        v0[6] = (short)f2h_bits(a1.z); v0[7] = (short)f2h_bits(a1.w);
        v1[0] = (short)f2h_bits(a2.x); v1[1] = (short)f2h_bits(a2.y);
        v1[2] = (short)f2h_bits(a2.z); v1[3] = (short)f2h_bits(a2.w);
        v1[4] = (short)f2h_bits(a3.x); v1[5] = (short)f2h_bits(a3.y);
        v1[6] = (short)f2h_bits(a3.z); v1[7] = (short)f2h_bits(a3.w);
        *(short8*)&hHi[tid * 16 + 0] = v0;
        *(short8*)&hHi[tid * 16 + 8] = v1;
    }

    const int wvid = tid >> 6;        // wave id 0..3 -> tile row
    const int L    = tid & 63;
    const int q    = L >> 4;          // quad
    const int lm   = L & 15;

    unsigned short* bufA = bufS;          // 64 rows x 72 shorts = 4608 shorts
    unsigned short* bufB = bufS + 4608;

    // ---- stage B(tap=0) into bufA: 512 short8 chunks, 2 per thread ----
    {
        int i0 = tid, i1 = 256 + tid;             // n = i>>3, ko = i&7
        short8 v0 = *(const short8*)(wt + (i0 >> 3) * 64 + (i0 & 7) * 8);
        short8 v1 = *(const short8*)(wt + (i1 >> 3) * 64 + (i1 & 7) * 8);
        *(short8*)(bufA + (i0 >> 3) * 72 + (i0 & 7) * 8) = v0;
        *(short8*)(bufA + (i1 >> 3) * 72 + (i1 & 7) * 8) = v1;
    }
    __syncthreads();

    f32x4 acc0[4] = {}, acc1[4] = {};   // 2 m-tiles x 4 n-tiles, 16x16 each

#pragma unroll 1
    for (int tap = 0; tap < 9; ++tap) {
        unsigned short* cur = (tap & 1) ? bufB : bufA;
        unsigned short* nxt = (tap & 1) ? bufA : bufB;

        // prefetch next tap's weights into registers (stores after compute)
        short8 p0, p1;
        if (tap < 8) {
            const unsigned short* wsrc = wt + (size_t)(tap + 1) * 4096;
            int i0 = tid, i1 = 256 + tid;
            p0 = *(const short8*)(wsrc + (i0 >> 3) * 64 + (i0 & 7) * 8);
            p1 = *(const short8*)(wsrc + (i1 >> 3) * 64 + (i1 & 7) * 8);
        }

        const int dy = tap / 3, dx = tap % 3;
        const int hb0 = (wvid + dy) * HWC + lm + dx;   // m-tile 0 halo pixel
        const int hb1 = hb0 + 16;                      // m-tile 1
        const int g0 = gsL[hb0];
        const int g1 = gsL[hb1];

#pragma unroll
        for (int ks = 0; ks < 2; ++ks) {
            const int gk = ks * 2 + (q >> 1);
            const int c0 = (q & 1) * 8;
            short8 z = (short8)0;
            short8 ah0 = *(const short8*)&hHi[hb0 * 16 + c0];
            short8 ah1 = *(const short8*)&hHi[hb1 * 16 + c0];
            ah0 = (g0 == gk) ? ah0 : z;
            ah1 = (g1 == gk) ? ah1 : z;

            short8 bh[4];
#pragma unroll
            for (int nt = 0; nt < 4; ++nt)
                bh[nt] = *(const short8*)(cur + (nt * 16 + lm) * 72 + ks * 32 + q * 8);
#pragma unroll
            for (int nt = 0; nt < 4; ++nt) {
                acc0[nt] = __builtin_amdgcn_mfma_f32_16x16x32_f16(as_h8(ah0), as_h8(bh[nt]), acc0[nt], 0, 0, 0);
                acc1[nt] = __builtin_amdgcn_mfma_f32_16x16x32_f16(as_h8(ah1), as_h8(bh[nt]), acc1[nt], 0, 0, 0);
            }
        }

        if (tap < 8) {
            int i0 = tid, i1 = 256 + tid;
            *(short8*)(nxt + (i0 >> 3) * 72 + (i0 & 7) * 8) = p0;
            *(short8*)(nxt + (i1 >> 3) * 72 + (i1 & 7) * 8) = p1;
        }
        __syncthreads();
    }

    // ---- epilogue: two passes, accumulators referenced literally ----
    const float SH = 0.015625f;          // 1/64 (weights pre-scaled x64)
    float* outS = (float*)bufS;          // per-wave region: 16 px * 68 floats

    EPI_STORE(acc0);
    __syncthreads();
    consume_tile(outS, bias, out_sel, out_idx, fix_cnt, fix_list, fix_cap,
                 tid, x0, y0, bz, 0);
    __syncthreads();
    EPI_STORE(acc1);
    __syncthreads();
    consume_tile(outS, bias, out_sel, out_idx, fix_cnt, fix_list, fix_cap,
                 tid, x0, y0, bz, 1);
}

// fp64 exact recompute; one wave per pixel, lane = oc. Uses wT [tap][ic][oc]
// (lane-coalesced). If the flag list overflowed its cap, deterministically
// recompute ALL pixels instead (slow path; output never depends on atomic order).
__global__ void fixup_kernel(const float* __restrict__ x, const int* __restrict__ gidx,
                             const float* __restrict__ wT, const float* __restrict__ bias,
                             float* __restrict__ out_sel, float* __restrict__ out_idx,
                             const unsigned* __restrict__ fix_cnt,
                             const unsigned* __restrict__ fix_list, unsigned fix_cap)
{
    unsigned n = *fix_cnt;
    const bool full = (n > fix_cap);
    const unsigned total = full ? (unsigned)NPIX_TOTAL : n;
    const int lane = threadIdx.x & 63;
    const unsigned nwaves = gridDim.x * (blockDim.x >> 6);
    unsigned widx = blockIdx.x * (blockDim.x >> 6) + (threadIdx.x >> 6);

    for (; widx < total; widx += nwaves) {
        unsigned opix = full ? widx : fix_list[widx];
        int b  = opix >> 16;
        int y  = (opix >> 8) & 255;
        int xc = opix & 255;
        double acc = (double)bias[lane];
        for (int dy = 0; dy < 3; ++dy) {
            int yy = y + dy - 1;
            if (yy < 0 || yy >= H) continue;
            for (int dx = 0; dx < 3; ++dx) {
                int xx = xc + dx - 1;
                if (xx < 0 || xx >= W) continue;
                size_t pix = ((size_t)b * H + yy) * W + xx;
                int g = gidx[pix];
                const float* xp = x + pix * 16;
                const float* wp = wT + (size_t)((dy * 3 + dx) * 64 + g * 16) * 64 + lane;
#pragma unroll
                for (int c = 0; c < 16; ++c)
                    acc = fma((double)wp[c * 64], (double)xp[c], acc);
            }
        }
        // group max within 16-lane clusters
        double m = acc;
        m = fmax(m, __shfl_xor(m, 1, 64));
        m = fmax(m, __shfl_xor(m, 2, 64));
        m = fmax(m, __shfl_xor(m, 4, 64));
        m = fmax(m, __shfl_xor(m, 8, 64));
        double g0 = __shfl(m, 0, 64), g1 = __shfl(m, 16, 64);
        double g2 = __shfl(m, 32, 64), g3 = __shfl(m, 48, 64);
        int bg = 0; double bb = g0;
        if (g1 > bb) { bb = g1; bg = 1; }
        if (g2 > bb) { bb = g2; bg = 2; }
        if (g3 > bb) { bb = g3; bg = 3; }
        if ((lane >> 4) == bg) out_sel[(size_t)opix * 16 + (lane & 15)] = (float)acc;
        if (lane == 0) out_idx[opix] = (float)bg;
    }
}

extern "C" void kernel_launch(void* const* d_in, const int* in_sizes, int n_in,
                              void* d_out, int out_size, void* d_ws, size_t ws_size,
                              hipStream_t stream) {
    const float* x    = (const float*)d_in[0];
    const int*   gidx = (const int*)d_in[1];
    const float* w    = (const float*)d_in[2];
    const float* bias = (const float*)d_in[3];

    unsigned short* wt = (unsigned short*)d_ws;                     // 73728 B
    float* wT          = (float*)((char*)d_ws + 73728);             // 147456 B
    unsigned* fix_cnt  = (unsigned*)((char*)d_ws + 221184);         // 16 B
    unsigned* fix_list = (unsigned*)((char*)d_ws + 221200);         // up to 2 MB

    // cap sized from the workspace the harness actually gave us (det. overflow fallback otherwise)
    size_t avail = (ws_size > 221200) ? (ws_size - 221200) / 4 : 0;
    unsigned fix_cap = (unsigned)(avail < (size_t)NPIX_TOTAL ? avail : (size_t)NPIX_TOTAL);

    float* out_sel = (float*)d_out;                               // 8*256*256*16
    float* out_idx = (float*)d_out + (size_t)BATCH * H * W * CIN; // 8*256*256

    wprep_kernel<<<144, 256, 0, stream>>>(w, wt, wT, fix_cnt);

    dim3 grid(W / TW, H / TH, BATCH);   // 8 x 64 x 8 = 4096 blocks
    ssconv_mfma_kernel<<<grid, 256, 0, stream>>>(x, gidx, wt, bias, out_sel, out_idx,
                                                 fix_cnt, fix_list, fix_cap);
    fixup_kernel<<<1024, 256, 0, stream>>>(x, gidx, wT, bias, out_sel, out_idx,
                                           fix_cnt, fix_list, fix_cap);
}